// Round 8
// baseline (74.630 us; speedup 1.0000x reference)
//
#include <hip/hip_runtime.h>
#include <cstddef>

#define DIM 2048
#define NTOK 8192
#define NEUMANN_ITERS 6

// Math (validated rounds 1-7):
//   omega = P Q^T, P=[U|V], Q=[sV|-sU], G = Q^T P  (16x16)
//   Y = (I - G/2)^{-1}(I + G/2)  via Neumann-Horner: Y <- B + 0.5*G*Y, B=I+G/2
//   out = x + sum_k c[k] P[:,k],
//   c[k] = 0.5*s* sum_j Z[k][j] b[j],  Z = I + Y,
//     b[j<8] = av[j], b[j>=8] = -au[j-8];  au = x.U, av = x.V
//
// Structural lessons baked in:
//  - No 1-block dispatches (rounds 2/4: ~100 us stall floor).
//  - No per-block redundant gram loop (round 5: ~380 us).
//  - No min-waves clause in launch_bounds (round 6: VGPR capped to 64 ->
//    spill, 221 us). Compiler picks ~108 VGPR -> 4 waves/SIMD allowed.
//  - Round 7: grid 512 = 2 blocks/CU = 2 waves/SIMD -> latency-bound at
//    61 us (VALUBusy 22%, hbm 28%). THIS round: d-split wave pairs ->
//    grid 1024, 4 waves/SIMD, same U/V amortization (4 rows/wave).
//  - No runtime indexing of register arrays.

// ---------------------------------------------------------------------------
// 1) Gram: one block per entry e=(q,i,j); 256 threads reduce over d=2048.
// ---------------------------------------------------------------------------
__global__ __launch_bounds__(256) void rora_gram(
    const float* __restrict__ U, const float* __restrict__ V,
    float* __restrict__ prod) {
  const int e = blockIdx.x;            // 0..191
  const int q = e >> 6;                // 0: U^T U, 1: U^T V, 2: V^T V
  const int i = (e >> 3) & 7, j = e & 7;
  const float* A = (q == 2) ? V : U;
  const float* B = (q == 0) ? U : V;
  const int t = threadIdx.x;
  float acc = 0.f;
#pragma unroll
  for (int s = 0; s < 8; ++s) {
    const int d = s * 256 + t;
    acc = fmaf(A[d * 8 + i], B[d * 8 + j], acc);
  }
#pragma unroll
  for (int m = 1; m < 64; m <<= 1) acc += __shfl_xor(acc, m, 64);
  __shared__ float wsum[4];
  if ((t & 63) == 0) wsum[t >> 6] = acc;
  __syncthreads();
  if (t == 0) prod[e] = (wsum[0] + wsum[1]) + (wsum[2] + wsum[3]);
}

// ---------------------------------------------------------------------------
// 2) Fused: 16x16 setup preamble + streaming main.
//    4 waves/block = 2 row-groups x 2 d-halves; 8 rows/block; grid 1024.
// ---------------------------------------------------------------------------
__global__ __launch_bounds__(256) void rora_fused(
    const float* __restrict__ x, const float* __restrict__ U,
    const float* __restrict__ V, const float* __restrict__ gate,
    const float* __restrict__ prod, float* __restrict__ out) {
  __shared__ float prodS[192];     // [q*64 + i*8 + j]
  __shared__ float Gs[16][17];
  __shared__ float Bm[16][17];
  __shared__ float Ya[16][17];
  __shared__ float Yb[16][17];
  __shared__ float ex[4][4][16];   // per-wave phase-1 partial dots
  const int t = threadIdx.x;

  if (t < 192) prodS[t] = prod[t];
  __syncthreads();
  const float sg = 1.f / (1.f + expf(-gate[0]));
  {
    const int r = t >> 4, c = t & 15;
    float g;
    if (r < 8) g = (c < 8) ? sg * prodS[64 + c * 8 + r]              // (V^T U)
                           : sg * prodS[128 + r * 8 + (c - 8)];      // (V^T V)
    else       g = (c < 8) ? -sg * prodS[(r - 8) * 8 + c]            // -(U^T U)
                           : -sg * prodS[64 + (r - 8) * 8 + (c - 8)];
    const float b = ((r == c) ? 1.f : 0.f) + 0.5f * g;
    Gs[r][c] = g;
    Bm[r][c] = b;
    Ya[r][c] = b;
  }
  __syncthreads();
  {
    const int r = t >> 4, c = t & 15;
#pragma unroll
    for (int m = 0; m < NEUMANN_ITERS; ++m) {   // ends in Ya (last m odd)
      const float (*Yp)[17] = (m & 1) ? Yb : Ya;
      float (*Yn)[17] = (m & 1) ? Ya : Yb;
      float acc = Bm[r][c];
#pragma unroll
      for (int j = 0; j < 16; ++j)
        acc = fmaf(0.5f * Gs[r][j], Yp[j][c], acc);
      Yn[r][c] = acc;
      __syncthreads();
    }
  }

  // ---- main: wave wv handles row-group (wv>>1), d-half (wv&1) ----
  const int wv = t >> 6, lane = t & 63;
  const int rowgrp = wv >> 1, dhalf = wv & 1;
  const int row0 = blockIdx.x * 8 + rowgrp * 4;
  const int dbase = dhalf * 1024;
  const float* xr = x + (size_t)row0 * DIM;
  float* orow = out + (size_t)row0 * DIM;
  const float4* U4 = (const float4*)U;
  const float4* V4 = (const float4*)V;

  float a[4][16];
#pragma unroll
  for (int r = 0; r < 4; ++r)
#pragma unroll
    for (int k = 0; k < 16; ++k) a[r][k] = 0.f;

  // phase 1: partial dots over this wave's d-half (16 iters)
#pragma unroll 2
  for (int i = 0; i < 16; ++i) {
    const int d = dbase + i * 64 + lane;
    const float4 ua = U4[2 * d], ub = U4[2 * d + 1];
    const float4 va = V4[2 * d], vb = V4[2 * d + 1];
    const float uu[16] = {ua.x, ua.y, ua.z, ua.w, ub.x, ub.y, ub.z, ub.w,
                          va.x, va.y, va.z, va.w, vb.x, vb.y, vb.z, vb.w};
    float xv[4];
#pragma unroll
    for (int r = 0; r < 4; ++r) xv[r] = xr[(size_t)r * DIM + d];
#pragma unroll
    for (int r = 0; r < 4; ++r) {
      const float xi = xv[r];
#pragma unroll
      for (int k = 0; k < 16; ++k) a[r][k] = fmaf(xi, uu[k], a[r][k]);
    }
  }

  // wave butterfly: full d-half sums on every lane
#pragma unroll
  for (int m = 1; m < 64; m <<= 1)
#pragma unroll
    for (int r = 0; r < 4; ++r)
#pragma unroll
      for (int k = 0; k < 16; ++k) a[r][k] += __shfl_xor(a[r][k], m, 64);

  // cross-wave pair exchange: a_full = a_self + a_partner (commutative ->
  // bitwise identical in both waves -> deterministic). Compile-time reg idx.
  if (lane == 0) {
#pragma unroll
    for (int r = 0; r < 4; ++r)
#pragma unroll
      for (int q = 0; q < 4; ++q)
        ((float4*)&ex[wv][r][0])[q] = make_float4(
            a[r][4 * q], a[r][4 * q + 1], a[r][4 * q + 2], a[r][4 * q + 3]);
  }
  __syncthreads();
  {
    const int pw = wv ^ 1;
#pragma unroll
    for (int r = 0; r < 4; ++r)
#pragma unroll
      for (int q = 0; q < 4; ++q) {
        const float4 p = ((const float4*)&ex[pw][r][0])[q];
        a[r][4 * q] += p.x;  a[r][4 * q + 1] += p.y;
        a[r][4 * q + 2] += p.z;  a[r][4 * q + 3] += p.w;
      }
  }

  // c[k] = 0.5*s * sum_j Z[k][j] b[j]; lane kk=lane&15 computes row kk.
  {
    const int kk = lane & 15;
    float zrow[16];
#pragma unroll
    for (int j = 0; j < 16; ++j)
      zrow[j] = Ya[kk][j] + ((j == kk) ? 1.f : 0.f);
    const float hs = 0.5f * sg;
    float cp[4];
#pragma unroll
    for (int r = 0; r < 4; ++r) {
      float s = 0.f;
#pragma unroll
      for (int j = 0; j < 8; ++j) {
        s = fmaf(zrow[j], a[r][8 + j], s);     //  Z[k][j]   * av[j]
        s = fmaf(-zrow[8 + j], a[r][j], s);    // -Z[k][8+j] * au[j]
      }
      cp[r] = hs * s;
    }
#pragma unroll
    for (int r = 0; r < 4; ++r)
#pragma unroll
      for (int k = 0; k < 16; ++k) a[r][k] = __shfl(cp[r], k, 64);
  }

  // phase 2: out[r][d] = x[r][d] + sum_{k<8} c[k]*U[d][k] + c[8+k]*V[d][k]
#pragma unroll 2
  for (int i = 0; i < 16; ++i) {
    const int d = dbase + i * 64 + lane;
    const float4 ua = U4[2 * d], ub = U4[2 * d + 1];
    const float4 va = V4[2 * d], vb = V4[2 * d + 1];
    const float uu[16] = {ua.x, ua.y, ua.z, ua.w, ub.x, ub.y, ub.z, ub.w,
                          va.x, va.y, va.z, va.w, vb.x, vb.y, vb.z, vb.w};
#pragma unroll
    for (int r = 0; r < 4; ++r) {
      float acc = xr[(size_t)r * DIM + d];
#pragma unroll
      for (int k = 0; k < 16; ++k) acc = fmaf(a[r][k], uu[k], acc);
      orow[(size_t)r * DIM + d] = acc;
    }
  }
}

extern "C" void kernel_launch(void* const* d_in, const int* in_sizes, int n_in,
                              void* d_out, int out_size, void* d_ws, size_t ws_size,
                              hipStream_t stream) {
  const float* x    = (const float*)d_in[0];
  const float* U    = (const float*)d_in[1];
  const float* V    = (const float*)d_in[2];
  const float* gate = (const float*)d_in[3];
  float* out = (float*)d_out;
  float* prodw = (float*)d_ws;   // 192 floats

  rora_gram<<<192, 256, 0, stream>>>(U, V, prodw);
  rora_fused<<<NTOK / 8, 256, 0, stream>>>(x, U, V, gate, prodw, out);
}

// Round 9
// 48.579 us; speedup vs baseline: 1.5363x; 1.5363x over previous
//
#include <hip/hip_runtime.h>
#include <cstddef>

#define DIM 2048
#define NTOK 8192
#define NEUMANN_ITERS 6

// Math (validated rounds 1-8):
//   omega = P Q^T, P=[U|V], Q=[sV|-sU], G = Q^T P  (16x16)
//   Y = (I - G/2)^{-1}(I + G/2)  via Neumann-Horner: Y <- B + 0.5*G*Y, B=I+G/2
//   out = x + sum_k c[k] P[:,k],
//   c[k] = 0.5*s* sum_j Z[k][j] b[j],  Z = I + Y,
//     b[j<8] = av[j], b[j>=8] = -au[j-8];  au = x.U, av = x.V
//
// Structural lessons baked in:
//  - No 1-block dispatches (rounds 2/4: ~100 us stall floor).
//  - No per-block redundant gram loop (round 5: ~380 us).
//  - No min-waves clause in launch_bounds (round 6: VGPR cap -> spill).
//  - Rounds 7/8: each wave re-read all of UV (128 KB) x2 from L2 (~1 GB
//    aggregate, UV > L1) -> latency-bound at 61-75 us. THIS round: UV
//    staged ONCE per block in LDS as bf16x8 planes (64 KB -> 2 blocks/CU,
//    16 waves/CU), conflict-free stride-16B ds_read_b128. bf16 error on
//    the ~2e-3 correction term ~1e-5 << 0.108 threshold.
//  - No runtime indexing of register arrays.

__device__ __forceinline__ unsigned pack2bf(float lo, float hi) {
  const unsigned ul = (__float_as_uint(lo) + 0x8000u) >> 16;
  const unsigned uh = (__float_as_uint(hi) + 0x8000u) & 0xffff0000u;
  return ul | uh;
}
#define B2F_LO(w) __uint_as_float((w) << 16)
#define B2F_HI(w) __uint_as_float((w) & 0xffff0000u)

// ---------------------------------------------------------------------------
// 1) Gram: one block per entry e=(q,i,j); 256 threads reduce over d=2048.
// ---------------------------------------------------------------------------
__global__ __launch_bounds__(256) void rora_gram(
    const float* __restrict__ U, const float* __restrict__ V,
    float* __restrict__ prod) {
  const int e = blockIdx.x;            // 0..191
  const int q = e >> 6;                // 0: U^T U, 1: U^T V, 2: V^T V
  const int i = (e >> 3) & 7, j = e & 7;
  const float* A = (q == 2) ? V : U;
  const float* B = (q == 0) ? U : V;
  const int t = threadIdx.x;
  float acc = 0.f;
#pragma unroll
  for (int s = 0; s < 8; ++s) {
    const int d = s * 256 + t;
    acc = fmaf(A[d * 8 + i], B[d * 8 + j], acc);
  }
#pragma unroll
  for (int m = 1; m < 64; m <<= 1) acc += __shfl_xor(acc, m, 64);
  __shared__ float wsum[4];
  if ((t & 63) == 0) wsum[t >> 6] = acc;
  __syncthreads();
  if (t == 0) prod[e] = (wsum[0] + wsum[1]) + (wsum[2] + wsum[3]);
}

// ---------------------------------------------------------------------------
// 2) Fused: UV->LDS bf16 staging + 16x16 setup + streaming main.
//    512 threads = 8 waves x 2 rows; grid 512; 2 blocks/CU.
// ---------------------------------------------------------------------------
__global__ __launch_bounds__(512) void rora_fused(
    const float* __restrict__ x, const float* __restrict__ U,
    const float* __restrict__ V, const float* __restrict__ gate,
    const float* __restrict__ prod, float* __restrict__ out) {
  __shared__ uint4 uvL[2][DIM];    // bf16x8: [0][d]=U[d][0..7], [1][d]=V[d][0..7]
  __shared__ float prodS[192];     // [q*64 + i*8 + j]
  __shared__ float Gs[16][17];
  __shared__ float Bm[16][17];
  __shared__ float Ya[16][17];
  __shared__ float Yb[16][17];
  const int t = threadIdx.x;

  // ---- stage U,V -> LDS (coalesced global float4; stride-16B LDS writes) ----
  {
    const float4* U4 = (const float4*)U;
    const float4* V4 = (const float4*)V;
#pragma unroll
    for (int rep = 0; rep < 4; ++rep) {
      const int d = rep * 512 + t;
      const float4 a = U4[2 * d], b = U4[2 * d + 1];
      uvL[0][d] = make_uint4(pack2bf(a.x, a.y), pack2bf(a.z, a.w),
                             pack2bf(b.x, b.y), pack2bf(b.z, b.w));
      const float4 c = V4[2 * d], e = V4[2 * d + 1];
      uvL[1][d] = make_uint4(pack2bf(c.x, c.y), pack2bf(c.z, c.w),
                             pack2bf(e.x, e.y), pack2bf(e.z, e.w));
    }
  }

  // ---- 16x16 setup (f32, from ws gram products) ----
  if (t < 192) prodS[t] = prod[t];
  __syncthreads();
  const float sg = 1.f / (1.f + expf(-gate[0]));
  if (t < 256) {
    const int r = t >> 4, c = t & 15;
    float g;
    if (r < 8) g = (c < 8) ? sg * prodS[64 + c * 8 + r]              // (V^T U)
                           : sg * prodS[128 + r * 8 + (c - 8)];      // (V^T V)
    else       g = (c < 8) ? -sg * prodS[(r - 8) * 8 + c]            // -(U^T U)
                           : -sg * prodS[64 + (r - 8) * 8 + (c - 8)];
    const float b = ((r == c) ? 1.f : 0.f) + 0.5f * g;
    Gs[r][c] = g;
    Bm[r][c] = b;
    Ya[r][c] = b;
  }
  __syncthreads();
#pragma unroll
  for (int m = 0; m < NEUMANN_ITERS; ++m) {   // ends in Ya (last m odd)
    if (t < 256) {
      const int r = t >> 4, c = t & 15;
      const float (*Yp)[17] = (m & 1) ? Yb : Ya;
      float (*Yn)[17] = (m & 1) ? Ya : Yb;
      float acc = Bm[r][c];
#pragma unroll
      for (int j = 0; j < 16; ++j)
        acc = fmaf(0.5f * Gs[r][j], Yp[j][c], acc);
      Yn[r][c] = acc;
    }
    __syncthreads();   // also orders uvL staging before phase-1 reads
  }

  // ---- main: 8 waves, 2 rows/wave ----
  const int wv = t >> 6, lane = t & 63;
  const int row0 = blockIdx.x * 16 + wv * 2;
  const float* xr0 = x + (size_t)row0 * DIM;
  const float* xr1 = xr0 + DIM;

  float a0[16], a1[16];
#pragma unroll
  for (int k = 0; k < 16; ++k) { a0[k] = 0.f; a1[k] = 0.f; }

  // phase 1: a = [x.U | x.V]; lane owns d = i*64+lane (stride-1)
#pragma unroll 4
  for (int i = 0; i < 32; ++i) {
    const int d = i * 64 + lane;
    const float x0 = xr0[d], x1 = xr1[d];
    const uint4 pu = uvL[0][d], pv = uvL[1][d];
    const float uu[16] = {
        B2F_LO(pu.x), B2F_HI(pu.x), B2F_LO(pu.y), B2F_HI(pu.y),
        B2F_LO(pu.z), B2F_HI(pu.z), B2F_LO(pu.w), B2F_HI(pu.w),
        B2F_LO(pv.x), B2F_HI(pv.x), B2F_LO(pv.y), B2F_HI(pv.y),
        B2F_LO(pv.z), B2F_HI(pv.z), B2F_LO(pv.w), B2F_HI(pv.w)};
#pragma unroll
    for (int k = 0; k < 16; ++k) {
      a0[k] = fmaf(x0, uu[k], a0[k]);
      a1[k] = fmaf(x1, uu[k], a1[k]);
    }
  }

  // wave butterfly: full-row dots on every lane
#pragma unroll
  for (int m = 1; m < 64; m <<= 1)
#pragma unroll
    for (int k = 0; k < 16; ++k) {
      a0[k] += __shfl_xor(a0[k], m, 64);
      a1[k] += __shfl_xor(a1[k], m, 64);
    }

  // c[k] = 0.5*s * sum_j Z[k][j] b[j]; lane kk=lane&15 computes row kk.
  {
    const int kk = lane & 15;
    float zrow[16];
#pragma unroll
    for (int j = 0; j < 16; ++j)
      zrow[j] = Ya[kk][j] + ((j == kk) ? 1.f : 0.f);
    const float hs = 0.5f * sg;
    float s0 = 0.f, s1 = 0.f;
#pragma unroll
    for (int j = 0; j < 8; ++j) {
      s0 = fmaf(zrow[j], a0[8 + j], s0);     //  Z[k][j]   * av[j]
      s0 = fmaf(-zrow[8 + j], a0[j], s0);    // -Z[k][8+j] * au[j]
      s1 = fmaf(zrow[j], a1[8 + j], s1);
      s1 = fmaf(-zrow[8 + j], a1[j], s1);
    }
    const float cp0 = hs * s0, cp1 = hs * s1;
#pragma unroll
    for (int k = 0; k < 16; ++k) {
      a0[k] = __shfl(cp0, k, 64);
      a1[k] = __shfl(cp1, k, 64);
    }
  }

  // phase 2: out[d] = x[d] + sum_k c[k]*uv[d][k]
  float* o0 = out + (size_t)row0 * DIM;
  float* o1 = o0 + DIM;
#pragma unroll 4
  for (int i = 0; i < 32; ++i) {
    const int d = i * 64 + lane;
    const float x0 = xr0[d], x1 = xr1[d];
    const uint4 pu = uvL[0][d], pv = uvL[1][d];
    const float uu[16] = {
        B2F_LO(pu.x), B2F_HI(pu.x), B2F_LO(pu.y), B2F_HI(pu.y),
        B2F_LO(pu.z), B2F_HI(pu.z), B2F_LO(pu.w), B2F_HI(pu.w),
        B2F_LO(pv.x), B2F_HI(pv.x), B2F_LO(pv.y), B2F_HI(pv.y),
        B2F_LO(pv.z), B2F_HI(pv.z), B2F_LO(pv.w), B2F_HI(pv.w)};
    float acc0 = x0, acc1 = x1;
#pragma unroll
    for (int k = 0; k < 16; ++k) {
      acc0 = fmaf(a0[k], uu[k], acc0);
      acc1 = fmaf(a1[k], uu[k], acc1);
    }
    o0[d] = acc0;
    o1[d] = acc1;
  }
}

extern "C" void kernel_launch(void* const* d_in, const int* in_sizes, int n_in,
                              void* d_out, int out_size, void* d_ws, size_t ws_size,
                              hipStream_t stream) {
  const float* x    = (const float*)d_in[0];
  const float* U    = (const float*)d_in[1];
  const float* V    = (const float*)d_in[2];
  const float* gate = (const float*)d_in[3];
  float* out = (float*)d_out;
  float* prodw = (float*)d_ws;   // 192 floats

  rora_gram<<<192, 256, 0, stream>>>(U, V, prodw);
  rora_fused<<<NTOK / 16, 512, 0, stream>>>(x, U, V, gate, prodw, out);
}

// Round 11
// 45.554 us; speedup vs baseline: 1.6383x; 1.0664x over previous
//
#include <hip/hip_runtime.h>
#include <hip/hip_fp16.h>
#include <cstddef>

#define DIM 2048
#define NTOK 8192
#define NEUMANN_ITERS 6

// Math (validated rounds 1-9):
//   omega = P Q^T, P=[U|V], Q=[sV|-sU], G = Q^T P  (16x16)
//   Y = (I - G/2)^{-1}(I + G/2)  via Neumann-Horner: Y <- B + 0.5*G*Y, B=I+G/2
//   out = x + sum_k c[k] P[:,k],
//   c[k] = 0.5*s* sum_j Z[k][j] b[j],  Z = I + Y,
//     b[j<8] = av[j], b[j>=8] = -au[j-8];  au = x.U, av = x.V
//
// Structural lessons baked in:
//  - No 1-block dispatches (rounds 2/4: ~100 us stall floor).
//  - No per-block redundant gram loop (round 5: ~380 us).
//  - No min-waves clause in launch_bounds (round 6: VGPR cap -> spill).
//  - UV staged once per block in LDS (round 9: killed the 1 GB L2 re-read).
//  - f16 pair-packing + v_dot2_f32_f16 / v_pk_fma_f16 (VALU ~2x cut);
//    DPP adds for butterfly levels 1/2/4/8 (LDS-pipe shuffles 3x cut).
//  - Round 10 compile lesson: cvt_pkrtz returns __fp16 ext_vector(2);
//    ALL half2-typed conversions must go through __builtin_bit_cast.
//  - No runtime indexing of register arrays.

typedef _Float16 h2 __attribute__((ext_vector_type(2)));

__device__ __forceinline__ unsigned pkh(float lo, float hi) {
  auto p = __builtin_amdgcn_cvt_pkrtz(lo, hi);   // v_cvt_pkrtz_f16_f32
  return __builtin_bit_cast(unsigned, p);
}
__device__ __forceinline__ h2 cvt2h(float lo, float hi) {
  auto p = __builtin_amdgcn_cvt_pkrtz(lo, hi);
  return __builtin_bit_cast(h2, p);
}

template <int CTRL>
__device__ __forceinline__ float dpp_add(float v) {
  const int t =
      __builtin_amdgcn_update_dpp(0, __float_as_int(v), CTRL, 0xf, 0xf, true);
  return v + __int_as_float(t);
}
// Full 64-lane sum: 4 VALU dpp-adds + 2 LDS shuffles. Each step pairs
// lanes holding disjoint partial sets (xor1, xor2, halves-of-8, halves-of-16).
__device__ __forceinline__ float wave_red(float v) {
  v = dpp_add<0xB1>(v);    // quad_perm [1,0,3,2]  (xor 1)
  v = dpp_add<0x4E>(v);    // quad_perm [2,3,0,1]  (xor 2)
  v = dpp_add<0x141>(v);   // row_half_mirror      (pairs halves of 8)
  v = dpp_add<0x140>(v);   // row_mirror           (pairs halves of 16)
  v += __shfl_xor(v, 16, 64);
  v += __shfl_xor(v, 32, 64);
  return v;
}

// ---------------------------------------------------------------------------
// 1) Gram: one block per entry e=(q,i,j); 256 threads reduce over d=2048.
// ---------------------------------------------------------------------------
__global__ __launch_bounds__(256) void rora_gram(
    const float* __restrict__ U, const float* __restrict__ V,
    float* __restrict__ prod) {
  const int e = blockIdx.x;            // 0..191
  const int q = e >> 6;                // 0: U^T U, 1: U^T V, 2: V^T V
  const int i = (e >> 3) & 7, j = e & 7;
  const float* A = (q == 2) ? V : U;
  const float* B = (q == 0) ? U : V;
  const int t = threadIdx.x;
  float acc = 0.f;
#pragma unroll
  for (int s = 0; s < 8; ++s) {
    const int d = s * 256 + t;
    acc = fmaf(A[d * 8 + i], B[d * 8 + j], acc);
  }
#pragma unroll
  for (int m = 1; m < 64; m <<= 1) acc += __shfl_xor(acc, m, 64);
  __shared__ float wsum[4];
  if ((t & 63) == 0) wsum[t >> 6] = acc;
  __syncthreads();
  if (t == 0) prod[e] = (wsum[0] + wsum[1]) + (wsum[2] + wsum[3]);
}

// ---------------------------------------------------------------------------
// 2) Fused: UV->LDS f16-pair staging + 16x16 setup + streaming main.
//    512 threads = 8 waves x 2 rows; grid 512; 2 blocks/CU.
//    uvQ[q][P].comp(m) = half2( W[2P][4q+m], W[2P+1][4q+m] ),
//      slots 0..7 = U columns, 8..15 = V columns.
// ---------------------------------------------------------------------------
__global__ __launch_bounds__(512) void rora_fused(
    const float* __restrict__ x, const float* __restrict__ U,
    const float* __restrict__ V, const float* __restrict__ gate,
    const float* __restrict__ prod, float* __restrict__ out) {
  __shared__ uint4 uvQ[4][DIM / 2];   // 64 KB
  __shared__ float prodS[192];        // [q*64 + i*8 + j]
  __shared__ float Gs[16][17];
  __shared__ float Bm[16][17];
  __shared__ float Ya[16][17];
  __shared__ float Yb[16][17];
  const int t = threadIdx.x;

  // ---- stage U,V -> LDS as f16 d-pairs ----
  {
    const float4* U4 = (const float4*)U;
    const float4* V4 = (const float4*)V;
#pragma unroll
    for (int rep = 0; rep < 2; ++rep) {
      const int P = rep * 512 + t;    // d-pair (2P, 2P+1)
      const float4 a0 = U4[4 * P + 0], a1 = U4[4 * P + 1];  // U[2P][0..7]
      const float4 a2 = U4[4 * P + 2], a3 = U4[4 * P + 3];  // U[2P+1][0..7]
      const float4 b0 = V4[4 * P + 0], b1 = V4[4 * P + 1];
      const float4 b2 = V4[4 * P + 2], b3 = V4[4 * P + 3];
      uvQ[0][P] = make_uint4(pkh(a0.x, a2.x), pkh(a0.y, a2.y),
                             pkh(a0.z, a2.z), pkh(a0.w, a2.w));
      uvQ[1][P] = make_uint4(pkh(a1.x, a3.x), pkh(a1.y, a3.y),
                             pkh(a1.z, a3.z), pkh(a1.w, a3.w));
      uvQ[2][P] = make_uint4(pkh(b0.x, b2.x), pkh(b0.y, b2.y),
                             pkh(b0.z, b2.z), pkh(b0.w, b2.w));
      uvQ[3][P] = make_uint4(pkh(b1.x, b3.x), pkh(b1.y, b3.y),
                             pkh(b1.z, b3.z), pkh(b1.w, b3.w));
    }
  }

  // ---- 16x16 setup (f32, from ws gram products) ----
  if (t < 192) prodS[t] = prod[t];
  __syncthreads();
  const float sg = 1.f / (1.f + expf(-gate[0]));
  if (t < 256) {
    const int r = t >> 4, c = t & 15;
    float g;
    if (r < 8) g = (c < 8) ? sg * prodS[64 + c * 8 + r]              // (V^T U)
                           : sg * prodS[128 + r * 8 + (c - 8)];      // (V^T V)
    else       g = (c < 8) ? -sg * prodS[(r - 8) * 8 + c]            // -(U^T U)
                           : -sg * prodS[64 + (r - 8) * 8 + (c - 8)];
    const float b = ((r == c) ? 1.f : 0.f) + 0.5f * g;
    Gs[r][c] = g;
    Bm[r][c] = b;
    Ya[r][c] = b;
  }
  __syncthreads();
#pragma unroll
  for (int m = 0; m < NEUMANN_ITERS; ++m) {   // ends in Ya (last m odd)
    if (t < 256) {
      const int r = t >> 4, c = t & 15;
      const float (*Yp)[17] = (m & 1) ? Yb : Ya;
      float (*Yn)[17] = (m & 1) ? Ya : Yb;
      float acc = Bm[r][c];
#pragma unroll
      for (int j = 0; j < 16; ++j)
        acc = fmaf(0.5f * Gs[r][j], Yp[j][c], acc);
      Yn[r][c] = acc;
    }
    __syncthreads();   // final barrier also orders uvQ staging before reads
  }

  // ---- main: 8 waves, 2 rows/wave; lane owns d-pairs P = i*64+lane ----
  const int wv = t >> 6, lane = t & 63;
  const int row0 = blockIdx.x * 16 + wv * 2;
  const float2* x2A = (const float2*)(x + (size_t)row0 * DIM);
  const float2* x2B = x2A + DIM / 2;

  float a0[16], a1[16];
#pragma unroll
  for (int k = 0; k < 16; ++k) { a0[k] = 0.f; a1[k] = 0.f; }

  // phase 1: a = [x.U | x.V]
#pragma unroll 4
  for (int i = 0; i < 16; ++i) {
    const int P = i * 64 + lane;
    const float2 xA = x2A[P], xB = x2B[P];
    const uint4 qa = uvQ[0][P], qb = uvQ[1][P];
    const uint4 qc = uvQ[2][P], qd = uvQ[3][P];
#if __has_builtin(__builtin_amdgcn_fdot2)
    const h2 xpA = cvt2h(xA.x, xA.y);
    const h2 xpB = cvt2h(xB.x, xB.y);
#define D2(acc, xp, u) \
  acc = __builtin_amdgcn_fdot2(xp, __builtin_bit_cast(h2, u), acc, false)
    D2(a0[0], xpA, qa.x);  D2(a0[1], xpA, qa.y);
    D2(a0[2], xpA, qa.z);  D2(a0[3], xpA, qa.w);
    D2(a0[4], xpA, qb.x);  D2(a0[5], xpA, qb.y);
    D2(a0[6], xpA, qb.z);  D2(a0[7], xpA, qb.w);
    D2(a0[8], xpA, qc.x);  D2(a0[9], xpA, qc.y);
    D2(a0[10], xpA, qc.z); D2(a0[11], xpA, qc.w);
    D2(a0[12], xpA, qd.x); D2(a0[13], xpA, qd.y);
    D2(a0[14], xpA, qd.z); D2(a0[15], xpA, qd.w);
    D2(a1[0], xpB, qa.x);  D2(a1[1], xpB, qa.y);
    D2(a1[2], xpB, qa.z);  D2(a1[3], xpB, qa.w);
    D2(a1[4], xpB, qb.x);  D2(a1[5], xpB, qb.y);
    D2(a1[6], xpB, qb.z);  D2(a1[7], xpB, qb.w);
    D2(a1[8], xpB, qc.x);  D2(a1[9], xpB, qc.y);
    D2(a1[10], xpB, qc.z); D2(a1[11], xpB, qc.w);
    D2(a1[12], xpB, qd.x); D2(a1[13], xpB, qd.y);
    D2(a1[14], xpB, qd.z); D2(a1[15], xpB, qd.w);
#undef D2
#else
    const __half2 uu[16] = {
        __builtin_bit_cast(__half2, qa.x), __builtin_bit_cast(__half2, qa.y),
        __builtin_bit_cast(__half2, qa.z), __builtin_bit_cast(__half2, qa.w),
        __builtin_bit_cast(__half2, qb.x), __builtin_bit_cast(__half2, qb.y),
        __builtin_bit_cast(__half2, qb.z), __builtin_bit_cast(__half2, qb.w),
        __builtin_bit_cast(__half2, qc.x), __builtin_bit_cast(__half2, qc.y),
        __builtin_bit_cast(__half2, qc.z), __builtin_bit_cast(__half2, qc.w),
        __builtin_bit_cast(__half2, qd.x), __builtin_bit_cast(__half2, qd.y),
        __builtin_bit_cast(__half2, qd.z), __builtin_bit_cast(__half2, qd.w)};
#pragma unroll
    for (int k = 0; k < 16; ++k) {
      a0[k] = fmaf(xA.x, __low2float(uu[k]), fmaf(xA.y, __high2float(uu[k]), a0[k]));
      a1[k] = fmaf(xB.x, __low2float(uu[k]), fmaf(xB.y, __high2float(uu[k]), a1[k]));
    }
#endif
  }

  // butterfly: 4 DPP VALU levels + 2 shuffles per value
#pragma unroll
  for (int k = 0; k < 16; ++k) {
    a0[k] = wave_red(a0[k]);
    a1[k] = wave_red(a1[k]);
  }

  // c[k] = 0.5*s * sum_j Z[k][j] b[j]; lane kk=lane&15 computes row kk.
  __half2 ch0[16], ch1[16];
  {
    const int kk = lane & 15;
    float zrow[16];
#pragma unroll
    for (int j = 0; j < 16; ++j)
      zrow[j] = Ya[kk][j] + ((j == kk) ? 1.f : 0.f);
    const float hs = 0.5f * sg;
    float s0 = 0.f, s1 = 0.f;
#pragma unroll
    for (int j = 0; j < 8; ++j) {
      s0 = fmaf(zrow[j], a0[8 + j], s0);     //  Z[k][j]   * av[j]
      s0 = fmaf(-zrow[8 + j], a0[j], s0);    // -Z[k][8+j] * au[j]
      s1 = fmaf(zrow[j], a1[8 + j], s1);
      s1 = fmaf(-zrow[8 + j], a1[j], s1);
    }
    const float cp0 = hs * s0, cp1 = hs * s1;
#pragma unroll
    for (int k = 0; k < 16; ++k) {
      ch0[k] = __float2half2_rn(__shfl(cp0, k, 64));
      ch1[k] = __float2half2_rn(__shfl(cp1, k, 64));
    }
  }

  // phase 2: out[2P..2P+1] = x + sum_k c[k]*W[.][k]  (packed f16 fma)
  float2* o2A = (float2*)(out + (size_t)row0 * DIM);
  float2* o2B = o2A + DIM / 2;
  const __half2 hz = __float2half2_rn(0.f);
#pragma unroll 4
  for (int i = 0; i < 16; ++i) {
    const int P = i * 64 + lane;
    const uint4 qa = uvQ[0][P], qb = uvQ[1][P];
    const uint4 qc = uvQ[2][P], qd = uvQ[3][P];
    __half2 sA = hz, sB = hz;
#define HF(u, k)                                               \
  sA = __hfma2(ch0[k], __builtin_bit_cast(__half2, u), sA);    \
  sB = __hfma2(ch1[k], __builtin_bit_cast(__half2, u), sB)
    HF(qa.x, 0);  HF(qa.y, 1);  HF(qa.z, 2);  HF(qa.w, 3);
    HF(qb.x, 4);  HF(qb.y, 5);  HF(qb.z, 6);  HF(qb.w, 7);
    HF(qc.x, 8);  HF(qc.y, 9);  HF(qc.z, 10); HF(qc.w, 11);
    HF(qd.x, 12); HF(qd.y, 13); HF(qd.z, 14); HF(qd.w, 15);
#undef HF
    const float2 xA = x2A[P], xB = x2B[P];
    float2 oA, oB;
    oA.x = xA.x + __low2float(sA);
    oA.y = xA.y + __high2float(sA);
    oB.x = xB.x + __low2float(sB);
    oB.y = xB.y + __high2float(sB);
    o2A[P] = oA;
    o2B[P] = oB;
  }
}

extern "C" void kernel_launch(void* const* d_in, const int* in_sizes, int n_in,
                              void* d_out, int out_size, void* d_ws, size_t ws_size,
                              hipStream_t stream) {
  const float* x    = (const float*)d_in[0];
  const float* U    = (const float*)d_in[1];
  const float* V    = (const float*)d_in[2];
  const float* gate = (const float*)d_in[3];
  float* out = (float*)d_out;
  float* prodw = (float*)d_ws;   // 192 floats

  rora_gram<<<192, 256, 0, stream>>>(U, V, prodw);
  rora_fused<<<NTOK / 16, 512, 0, stream>>>(x, U, V, gate, prodw, out);
}